// Round 7
// baseline (1025.377 us; speedup 1.0000x reference)
//
#include <hip/hip_runtime.h>

typedef unsigned short ushort_t;
typedef _Float16 half8 __attribute__((ext_vector_type(8)));
typedef short short8 __attribute__((ext_vector_type(8)));
typedef float floatx4 __attribute__((ext_vector_type(4)));

#define NCC 65536
#define NPP 1024
#define DD 256
#define NCHUNK 64
#define VROW 36                      // padded vT tile row, halves (72B)
#define VTILE_B (256 * VROW * 2)     // 18432 B per 32-candidate vT tile

static __device__ __forceinline__ ushort_t f2h_bits(float x) {
  _Float16 h = (_Float16)x;
  return __builtin_bit_cast(ushort_t, h);
}
static __device__ __forceinline__ ushort_t f2bf_bits(float x) {
  unsigned u = __builtin_bit_cast(unsigned, x);
  unsigned r = (u + 0x7FFFu + ((u >> 16) & 1u)) >> 16;
  return (ushort_t)r;
}
// native RNE f32->bf16 (fptrunc; compiler may fuse pairs into v_cvt_pk_bf16_f32)
static __device__ __forceinline__ ushort_t f2bf_cast(float x) {
  __bf16 h = (__bf16)x;
  return __builtin_bit_cast(ushort_t, h);
}

// async global->LDS DMA, 16B per lane (idiom verified rounds 2-3)
static __device__ __forceinline__ void dma16(const void* g, void* l) {
  __builtin_amdgcn_global_load_lds((const __attribute__((address_space(1))) unsigned int*)g,
                                   (__attribute__((address_space(3))) unsigned int*)l, 16, 0, 0);
}

static __device__ __forceinline__ short8 mk_s8(uint2 lo, uint2 hi) {
  uint4 u;
  u.x = lo.x; u.y = lo.y; u.z = hi.x; u.w = hi.y;
  return __builtin_bit_cast(short8, u);
}

// ---------------------------------------------------------------------------
// K0: transpose Wq/Wk (fp32 [k][n]) -> WT (f16 [n][k]), k' = k ^ ((n&7)<<3)
// ---------------------------------------------------------------------------
__global__ __launch_bounds__(256) void wt_prep(const float* __restrict__ Wq,
                                               const float* __restrict__ Wk,
                                               ushort_t* __restrict__ WqT,
                                               ushort_t* __restrict__ WkT) {
  __shared__ __align__(16) ushort_t lt[64][80];
  const float* W = blockIdx.y ? Wk : Wq;
  ushort_t* WT = blockIdx.y ? WkT : WqT;
  const int k0 = ((int)blockIdx.x & 3) * 64, n0 = ((int)blockIdx.x >> 2) * 64;
  const int t = threadIdx.x;
#pragma unroll
  for (int i = 0; i < 4; i++) {
    int f = t + 256 * i;
    int k = f >> 4, j = (f & 15) * 4;
    const float4 v = *(const float4*)&W[(size_t)(k0 + k) * DD + n0 + j];
    lt[j + 0][k] = f2h_bits(v.x);
    lt[j + 1][k] = f2h_bits(v.y);
    lt[j + 2][k] = f2h_bits(v.z);
    lt[j + 3][k] = f2h_bits(v.w);
  }
  __syncthreads();
#pragma unroll
  for (int i = 0; i < 2; i++) {
    int f = t + 256 * i;
    int nl = f >> 3, grp = f & 7;
    int n = n0 + nl;
    int kp = k0 + ((grp ^ (n & 7)) * 8);
    *(uint4*)&WT[(size_t)n * DD + kp] = *(const uint4*)&lt[nl][grp * 8];
  }
}

// ---------------------------------------------------------------------------
// K1: fused GEMM producing keyf (scaled, k-group swizzled) + query (plain),
// f16, PLUS vTb (bf16 transposed box_feat) for the kf blocks. Single
// box_feat read (round 6), register-preloaded; pass loop produces both
// lds_a (f16 scaled) and the lt transpose staging (bf16).
// ---------------------------------------------------------------------------
__global__ __launch_bounds__(256) void prep_gemm(
    const float* __restrict__ box_feat, const float* __restrict__ points_feat,
    const float* __restrict__ centers, const float* __restrict__ scales,
    const ushort_t* __restrict__ WqT, const ushort_t* __restrict__ WkT,
    const float* __restrict__ bq, const float* __restrict__ bk,
    ushort_t* __restrict__ q_out, ushort_t* __restrict__ kf_out,
    ushort_t* __restrict__ vTb, float2* __restrict__ xy) {
  __shared__ __align__(16) ushort_t lds_a[64][264];
  __shared__ __align__(16) ushort_t lds_b[64 * 256];
  __shared__ __align__(16) ushort_t lds_o[64][72];   // epilogue staging; also vT transpose staging
  __shared__ float lds_s[64];

  const int t = threadIdx.x;
  const bool isQ = (blockIdx.x >= (NCC / 64));
  const int row0 = isQ ? ((int)blockIdx.x - NCC / 64) * 64 : (int)blockIdx.x * 64;
  const float* In = isQ ? points_feat : box_feat;
  const ushort_t* WT = isQ ? WqT : WkT;
  const float* Bi = isQ ? bq : bk;
  ushort_t* Out = isQ ? q_out : kf_out;
  const int swz = isQ ? 0 : 7;

  // ---- preload the whole 64x256 row-tile: 4 rows x 4 col-blocks per thread ----
  const int r0 = t >> 4;        // 0..15: base row
  const int cj = (t & 15) * 4;  // col within a 64-col block
  float4 vld[4][4];             // [p(col-block)][i2(row-step)] -- static indices only
#pragma unroll
  for (int p = 0; p < 4; ++p)
#pragma unroll
    for (int i2 = 0; i2 < 4; ++i2)
      vld[p][i2] = *(const float4*)&In[(size_t)(row0 + r0 + 16 * i2) * DD + p * 64 + cj];

  if (t < 64) {
    float s = 1.0f;
    if (!isQ) {
      int c = row0 + t;
      float stride = centers[c * 4 + 3];
      int lvl = (int)(log2f(stride) + 0.5f) - 3;
      lvl = lvl < 0 ? 0 : (lvl > 4 ? 4 : lvl);
      s = scales[lvl];
      float hf = floorf(centers[c * 4 + 2] * 0.5f);
      xy[c] = make_float2(centers[c * 4 + 1] + hf, centers[c * 4 + 0] + hf);
    }
    lds_s[t] = s;
  }
  __syncthreads();

  float sc[4];
#pragma unroll
  for (int i2 = 0; i2 < 4; ++i2) sc[i2] = lds_s[r0 + 16 * i2];

  // ---- fused convert: lds_a (f16 scaled) + lt (bf16 transposed) per pass ----
  {
    ushort_t(*lt)[72] = lds_o;
#pragma unroll
    for (int p = 0; p < 4; ++p) {
#pragma unroll
      for (int i2 = 0; i2 < 4; ++i2) {
        const float4 v = vld[p][i2];
        const int row = r0 + 16 * i2;
        const float s = sc[i2];
        ushort_t h0 = f2h_bits(v.x * s), h1 = f2h_bits(v.y * s);
        ushort_t h2 = f2h_bits(v.z * s), h3 = f2h_bits(v.w * s);
        *(uint2*)&lds_a[row][p * 64 + cj] =
            make_uint2((unsigned)h0 | ((unsigned)h1 << 16), (unsigned)h2 | ((unsigned)h3 << 16));
        if (!isQ) {
          lt[cj + 0][row] = f2bf_bits(v.x);
          lt[cj + 1][row] = f2bf_bits(v.y);
          lt[cj + 2][row] = f2bf_bits(v.z);
          lt[cj + 3][row] = f2bf_bits(v.w);
        }
      }
      if (!isQ) {  // block-uniform -> barriers legal
        __syncthreads();
#pragma unroll
        for (int i3 = 0; i3 < 2; i3++) {
          int f = t + 256 * i3;  // 0..511 -> 64 d x 8 c-groups
          int d = f >> 3, jg = f & 7;
          int tile = (row0 >> 5) + (jg >> 2);
          size_t ob = (size_t)tile * (256 * VROW) + (size_t)(p * 64 + d) * VROW + (jg & 3) * 8;
          const uint2* src = (const uint2*)&lt[d][jg * 8];
          *(uint2*)&vTb[ob] = src[0];
          *(uint2*)&vTb[ob + 4] = src[1];
        }
        __syncthreads();  // copyout done before next pass overwrites lt
      }
    }
  }

  const int w = t >> 6, lane = t & 63, qd = lane >> 4, n = lane & 15;
  const int sw8 = (n & 7) * 8;

  for (int g = 0; g < 4; ++g) {
    __syncthreads();  // lds_b/lds_o reusable; covers A-stage + vT passes at g=0
#pragma unroll
    for (int j = 0; j < 8; ++j) {
      int sg = w * 8 + j;
      dma16(&WT[(size_t)g * 64 * DD + sg * 512 + lane * 8], &lds_b[sg * 512 + lane * 8]);
    }
    __syncthreads();

    floatx4 acc[4] = {};
#pragma unroll
    for (int s = 0; s < 8; s++) {
      half8 af = __builtin_bit_cast(half8, *(const uint4*)&lds_a[w * 16 + n][s * 32 + qd * 8]);
      int off = (s * 32 + qd * 8) ^ sw8;
#pragma unroll
      for (int nt = 0; nt < 4; ++nt) {
        half8 bf = __builtin_bit_cast(half8, *(const uint4*)&lds_b[(nt * 16 + n) * 256 + off]);
        acc[nt] = __builtin_amdgcn_mfma_f32_16x16x32_f16(af, bf, acc[nt], 0, 0, 0);
      }
    }
    // epilogue to lds_o (C/D: row=4qd+r, col=nt*16+n)
#pragma unroll
    for (int nt = 0; nt < 4; ++nt) {
      float b = Bi[g * 64 + nt * 16 + n];
#pragma unroll
      for (int r = 0; r < 4; r++) lds_o[w * 16 + qd * 4 + r][nt * 16 + n] = f2h_bits(acc[nt][r] + b);
    }
    __syncthreads();
    // coalesced copy-out with kf swizzle
#pragma unroll
    for (int i = 0; i < 2; i++) {
      int idx = t * 2 + i;
      int r = idx >> 3, grp = idx & 7;
      uint4 v = *(const uint4*)&lds_o[r][grp * 8];
      int grpS = grp ^ (swz & (r & 7));
      *(uint4*)&Out[(size_t)(row0 + r) * DD + (g * 8 + grpS) * 8] = v;
    }
  }
}

// ---------------------------------------------------------------------------
// K3: fused attention. Round-5 body (clean, 122.4us) with ONE structural
// change: occupancy 2 -> 4 blocks/CU (16 waves/CU) by cutting LDS 78848 ->
// 40960 B. (a) lds_v dropped -- PV reads V directly from global vTb
// (L2/L3-resident; ~10 TB/s aggregate L2 demand vs 34.5 ceiling; latency
// hidden by 4 waves/SIMD). (b) lds_p inner dim 36->32 (fits 40960 exactly).
// Rationale: measured wall/iter = 9190 cyc vs busiest pipe ~3450 cyc ->
// latency-bound at 2 waves/SIMD; occupancy is the lever, not inst count.
// Body otherwise byte-identical (no local arrays / asm packing -- rule #20,
// rounds 1-3 scratch-spill lesson). Tripwires: occupancy ~20 -> LDS
// granularity; FETCH >100MB -> L2 thrash from 4x V demand.
// ---------------------------------------------------------------------------
template <bool PART>
__global__ __launch_bounds__(256, 4) void attn_kernel(
    const ushort_t* __restrict__ qf16, const ushort_t* __restrict__ kf16,
    const ushort_t* __restrict__ vTb, const float2* __restrict__ xy,
    const float* __restrict__ boxes, float* __restrict__ acc_out,
    float* __restrict__ den_out) {
  __shared__ __align__(16) ushort_t lds_k[2][32 * 256];   // kf tile (swizzled rows)
  __shared__ __align__(16) ushort_t lds_p[4][32][32];     // per-wave P^T bf16

  const int t = threadIdx.x;
  const int w = t >> 6, lane = t & 63, qd = lane >> 4, n = lane & 15;
  const int chunk = blockIdx.x;
  const int p0w = blockIdx.y * 128 + w * 32;
  const int cchunk = chunk * 1024;
  const int sw16 = (n & 7) * 16;  // byte XOR for kf frag reads

  half8 qfr[2][8];
  float4 bxv[2];
#pragma unroll
  for (int pt = 0; pt < 2; ++pt) {
    int p = p0w + pt * 16 + n;
#pragma unroll
    for (int s = 0; s < 8; s++)
      qfr[pt][s] =
          __builtin_bit_cast(half8, *(const uint4*)&qf16[(size_t)p * DD + s * 32 + qd * 8]);
    bxv[pt] = *(const float4*)&boxes[p * 4];
  }

  floatx4 macc[2][16] = {};
  float dsum0 = 0.f, dsum1 = 0.f;

  // stage kf only (V is read direct-from-global in PV)
  auto stage = [&](int it, int buf) {
    const size_t kbase = (size_t)(cchunk + it * 32) * DD * 2;  // bytes
#pragma unroll
    for (int j = 0; j < 4; ++j) {
      int i = w * 4 + j;
      dma16((const char*)kf16 + kbase + i * 1024 + lane * 16,
            (char*)lds_k[buf] + i * 1024 + lane * 16);
    }
  };

  stage(0, 0);

  for (int it = 0; it < 32; ++it) {
    const int buf = it & 1;
    const int cb = cchunk + it * 32;
    __syncthreads();  // drains stage(it); prev iter's reads of buf^1 done
    if (it + 1 < 32) stage(it + 1, buf ^ 1);  // drains at NEXT barrier

    // QK^T from lds_k[buf] (XOR-swizzled rows, bank-balanced)
#pragma unroll
    for (int t2 = 0; t2 < 2; ++t2) {
      const char* krow = (const char*)lds_k[buf] + (t2 * 16 + n) * 512;
      floatx4 a0 = {}, a1 = {};
#pragma unroll
      for (int s = 0; s < 8; s++) {
        half8 af = __builtin_bit_cast(half8, *(const uint4*)(krow + ((s * 64 + qd * 16) ^ sw16)));
        a0 = __builtin_amdgcn_mfma_f32_16x16x32_f16(af, qfr[0][s], a0, 0, 0, 0);
        a1 = __builtin_amdgcn_mfma_f32_16x16x32_f16(af, qfr[1][s], a1, 0, 0, 0);
      }
      unsigned pk00 = 0, pk01 = 0, pk10 = 0, pk11 = 0;
#pragma unroll
      for (int r = 0; r < 4; r++) {
        int cl = t2 * 16 + qd * 4 + r;
        float2 pxy = xy[cb + cl];  // L1/L2-resident, wave-uniform per 16 lanes
        {
          float mn = fminf(fminf(pxy.x - bxv[0].x, pxy.y - bxv[0].y),
                           fminf(bxv[0].z - pxy.x, bxv[0].w - pxy.y));
          float sim = __builtin_amdgcn_fmed3f(a0[r], -50.f, 50.f);
          float e = (mn > 0.f) ? __builtin_amdgcn_exp2f((sim - 50.f) * 1.44269504f) : 0.f;
          dsum0 += e;
          unsigned b = (unsigned)f2bf_cast(e);
          if (r == 0) pk00 = b;
          else if (r == 1) pk00 |= b << 16;
          else if (r == 2) pk01 = b;
          else pk01 |= b << 16;
        }
        {
          float mn = fminf(fminf(pxy.x - bxv[1].x, pxy.y - bxv[1].y),
                           fminf(bxv[1].z - pxy.x, bxv[1].w - pxy.y));
          float sim = __builtin_amdgcn_fmed3f(a1[r], -50.f, 50.f);
          float e = (mn > 0.f) ? __builtin_amdgcn_exp2f((sim - 50.f) * 1.44269504f) : 0.f;
          dsum1 += e;
          unsigned b = (unsigned)f2bf_cast(e);
          if (r == 0) pk10 = b;
          else if (r == 1) pk10 |= b << 16;
          else if (r == 2) pk11 = b;
          else pk11 |= b << 16;
        }
      }
      *(uint2*)&lds_p[w][n][t2 * 16 + qd * 4] = make_uint2(pk00, pk01);
      *(uint2*)&lds_p[w][16 + n][t2 * 16 + qd * 4] = make_uint2(pk10, pk11);
    }
    // same-wave LDS RAW on lds_p (DS ops only; DMA uses vmcnt)
    __asm__ volatile("s_waitcnt lgkmcnt(0)" ::: "memory");

    const char* pr0 = (const char*)&lds_p[w][n][0];
    const char* pr1 = (const char*)&lds_p[w][16 + n][0];
    short8 a20 = mk_s8(*(const uint2*)(pr0 + qd * 16), *(const uint2*)(pr0 + qd * 16 + 8));
    short8 a21 = mk_s8(*(const uint2*)(pr1 + qd * 16), *(const uint2*)(pr1 + qd * 16 + 8));
    // V direct from global (L2/L3-resident vTb tile for this iteration)
    const char* vg = (const char*)vTb + (size_t)((cchunk >> 5) + it) * VTILE_B;
#pragma unroll
    for (int dt = 0; dt < 16; ++dt) {
      const char* vrow = vg + (dt * 16 + n) * (VROW * 2);
      short8 b2 = mk_s8(*(const uint2*)(vrow + qd * 16), *(const uint2*)(vrow + qd * 16 + 8));
      macc[0][dt] = __builtin_amdgcn_mfma_f32_16x16x32_bf16(a20, b2, macc[0][dt], 0, 0, 0);
      macc[1][dt] = __builtin_amdgcn_mfma_f32_16x16x32_bf16(a21, b2, macc[1][dt], 0, 0, 0);
    }
  }

  dsum0 += __shfl_xor(dsum0, 16, 64);
  dsum0 += __shfl_xor(dsum0, 32, 64);
  dsum1 += __shfl_xor(dsum1, 16, 64);
  dsum1 += __shfl_xor(dsum1, 32, 64);

  if (PART) {
    if (lane < 16) {
      den_out[(size_t)chunk * NPP + p0w + n] = dsum0;
      den_out[(size_t)chunk * NPP + p0w + 16 + n] = dsum1;
    }
    float* ab = acc_out + (size_t)chunk * NPP * DD;
#pragma unroll
    for (int pt = 0; pt < 2; ++pt)
#pragma unroll
      for (int dt = 0; dt < 16; ++dt)
#pragma unroll
        for (int r = 0; r < 4; r++)
          ab[(size_t)(p0w + pt * 16 + qd * 4 + r) * DD + dt * 16 + n] = macc[pt][dt][r];
  } else {
    if (lane < 16) {
      atomicAdd(&den_out[p0w + n], dsum0);
      atomicAdd(&den_out[p0w + 16 + n], dsum1);
    }
#pragma unroll
    for (int pt = 0; pt < 2; ++pt)
#pragma unroll
      for (int dt = 0; dt < 16; ++dt)
#pragma unroll
        for (int r = 0; r < 4; r++)
          atomicAdd(&acc_out[(size_t)(p0w + pt * 16 + qd * 4 + r) * DD + dt * 16 + n],
                    macc[pt][dt][r]);
  }
}

// ---------------------------------------------------------------------------
// K4a: reduce partials over chunks + finalize (PART path)
// ---------------------------------------------------------------------------
__global__ __launch_bounds__(256) void reduce_finalize(const float* __restrict__ points_feat,
                                                       const float* __restrict__ acc_part,
                                                       const float* __restrict__ den_part,
                                                       float* __restrict__ out) {
  const int p = blockIdx.x, t = threadIdx.x;
  float s = 0.f;
#pragma unroll 4
  for (int c = 0; c < NCHUNK; ++c) s += acc_part[((size_t)c * NPP + p) * DD + t];
  float dn = den_part[(size_t)(t & 63) * NPP + p];
#pragma unroll
  for (int o = 1; o < 64; o <<= 1) dn += __shfl_xor(dn, o, 64);
  float m = (dn > 0.f) ? s / dn : 0.f;
  out[(size_t)p * DD + t] = points_feat[(size_t)p * DD + t] + m;
}

// K4b: atomic-path finalize
__global__ void finalize(const float* __restrict__ points_feat, const float* __restrict__ acc,
                         const float* __restrict__ den, float* __restrict__ out) {
  int p = blockIdx.x, d = threadIdx.x;
  float dn = den[p];
  float m = (dn > 0.f) ? acc[p * DD + d] / dn : 0.f;
  out[p * DD + d] = points_feat[p * DD + d] + m;
}

extern "C" void kernel_launch(void* const* d_in, const int* in_sizes, int n_in, void* d_out,
                              int out_size, void* d_ws, size_t ws_size, hipStream_t stream) {
  const float* points_feat = (const float*)d_in[0];
  const float* box_feat = (const float*)d_in[1];
  const float* centers = (const float*)d_in[2];
  const float* boxes = (const float*)d_in[3];
  const float* Wq = (const float*)d_in[4];
  const float* bq = (const float*)d_in[5];
  const float* Wk = (const float*)d_in[6];
  const float* bk = (const float*)d_in[7];
  const float* scales = (const float*)d_in[8];

  char* p = (char*)d_ws;
  ushort_t* ws_q = (ushort_t*)p;        p += (size_t)NPP * DD * 2;
  ushort_t* ws_kf = (ushort_t*)p;       p += (size_t)NCC * DD * 2;
  ushort_t* ws_vTb = (ushort_t*)p;      p += (size_t)(NCC / 32) * VTILE_B;
  float2* ws_xy = (float2*)p;           p += (size_t)NCC * 8;
  ushort_t* ws_wqT = (ushort_t*)p;      p += (size_t)DD * DD * 2;
  ushort_t* ws_wkT = (ushort_t*)p;      p += (size_t)DD * DD * 2;
  float* ws_den = (float*)p;            p += (size_t)NCHUNK * NPP * 4;
  float* ws_acc = (float*)p;
  size_t need_part = (size_t)(p - (char*)d_ws) + (size_t)NCHUNK * NPP * DD * 4;
  const bool part = ws_size >= need_part;

  wt_prep<<<dim3(16, 2), 256, 0, stream>>>(Wq, Wk, ws_wqT, ws_wkT);
  prep_gemm<<<NCC / 64 + NPP / 64, 256, 0, stream>>>(box_feat, points_feat, centers, scales,
                                                     ws_wqT, ws_wkT, bq, bk, ws_q, ws_kf,
                                                     ws_vTb, ws_xy);
  if (part) {
    attn_kernel<true><<<dim3(NCHUNK, 8), 256, 0, stream>>>(ws_q, ws_kf, ws_vTb, ws_xy, boxes,
                                                           ws_acc, ws_den);
    reduce_finalize<<<NPP, 256, 0, stream>>>(points_feat, ws_acc, ws_den, (float*)d_out);
  } else {
    hipMemsetAsync(ws_den, 0, ((size_t)NPP * DD + NPP) * sizeof(float), stream);
    float* acc1 = ws_den + NPP;  // reuse region: den (1024) + acc (1024*256)
    attn_kernel<false><<<dim3(NCHUNK, 8), 256, 0, stream>>>(ws_q, ws_kf, ws_vTb, ws_xy, boxes,
                                                            acc1, ws_den);
    finalize<<<NPP, DD, 0, stream>>>(points_feat, acc1, ws_den, (float*)d_out);
  }
}

// Round 8
// 267.783 us; speedup vs baseline: 3.8291x; 3.8291x over previous
//
#include <hip/hip_runtime.h>

typedef unsigned short ushort_t;
typedef _Float16 half8 __attribute__((ext_vector_type(8)));
typedef short short8 __attribute__((ext_vector_type(8)));
typedef float floatx4 __attribute__((ext_vector_type(4)));

#define NCC 65536
#define NPP 1024
#define DD 256
#define NCHUNK 64
#define VROW 36                      // padded vT tile row, halves (72B: 16-phase banks)
#define VTILE_B (256 * VROW * 2)     // 18432 B per 32-candidate vT tile

static __device__ __forceinline__ ushort_t f2h_bits(float x) {
  _Float16 h = (_Float16)x;
  return __builtin_bit_cast(ushort_t, h);
}
static __device__ __forceinline__ ushort_t f2bf_bits(float x) {
  unsigned u = __builtin_bit_cast(unsigned, x);
  unsigned r = (u + 0x7FFFu + ((u >> 16) & 1u)) >> 16;
  return (ushort_t)r;
}
// native RNE f32->bf16 (fptrunc; compiler may fuse pairs into v_cvt_pk_bf16_f32)
static __device__ __forceinline__ ushort_t f2bf_cast(float x) {
  __bf16 h = (__bf16)x;
  return __builtin_bit_cast(ushort_t, h);
}

// async global->LDS DMA, 16B per lane (idiom verified rounds 2-3)
static __device__ __forceinline__ void dma16(const void* g, void* l) {
  __builtin_amdgcn_global_load_lds((const __attribute__((address_space(1))) unsigned int*)g,
                                   (__attribute__((address_space(3))) unsigned int*)l, 16, 0, 0);
}

static __device__ __forceinline__ short8 mk_s8(uint2 lo, uint2 hi) {
  uint4 u;
  u.x = lo.x; u.y = lo.y; u.z = hi.x; u.w = hi.y;
  return __builtin_bit_cast(short8, u);
}

// ---------------------------------------------------------------------------
// K0: transpose Wq/Wk (fp32 [k][n]) -> WT (f16 [n][k]), k' = k ^ ((n&7)<<3)
// ---------------------------------------------------------------------------
__global__ __launch_bounds__(256) void wt_prep(const float* __restrict__ Wq,
                                               const float* __restrict__ Wk,
                                               ushort_t* __restrict__ WqT,
                                               ushort_t* __restrict__ WkT) {
  __shared__ __align__(16) ushort_t lt[64][80];
  const float* W = blockIdx.y ? Wk : Wq;
  ushort_t* WT = blockIdx.y ? WkT : WqT;
  const int k0 = ((int)blockIdx.x & 3) * 64, n0 = ((int)blockIdx.x >> 2) * 64;
  const int t = threadIdx.x;
#pragma unroll
  for (int i = 0; i < 4; i++) {
    int f = t + 256 * i;
    int k = f >> 4, j = (f & 15) * 4;
    const float4 v = *(const float4*)&W[(size_t)(k0 + k) * DD + n0 + j];
    lt[j + 0][k] = f2h_bits(v.x);
    lt[j + 1][k] = f2h_bits(v.y);
    lt[j + 2][k] = f2h_bits(v.z);
    lt[j + 3][k] = f2h_bits(v.w);
  }
  __syncthreads();
#pragma unroll
  for (int i = 0; i < 2; i++) {
    int f = t + 256 * i;
    int nl = f >> 3, grp = f & 7;
    int n = n0 + nl;
    int kp = k0 + ((grp ^ (n & 7)) * 8);
    *(uint4*)&WT[(size_t)n * DD + kp] = *(const uint4*)&lt[nl][grp * 8];
  }
}

// ---------------------------------------------------------------------------
// K1: fused GEMM producing keyf (scaled, k-group swizzled) + query (plain),
// f16, PLUS vTb (bf16 transposed box_feat) for the kf blocks. Single
// box_feat read (round 6), register-preloaded; pass loop produces both
// lds_a (f16 scaled) and the lt transpose staging (bf16).
// ---------------------------------------------------------------------------
__global__ __launch_bounds__(256) void prep_gemm(
    const float* __restrict__ box_feat, const float* __restrict__ points_feat,
    const float* __restrict__ centers, const float* __restrict__ scales,
    const ushort_t* __restrict__ WqT, const ushort_t* __restrict__ WkT,
    const float* __restrict__ bq, const float* __restrict__ bk,
    ushort_t* __restrict__ q_out, ushort_t* __restrict__ kf_out,
    ushort_t* __restrict__ vTb, float2* __restrict__ xy) {
  __shared__ __align__(16) ushort_t lds_a[64][264];
  __shared__ __align__(16) ushort_t lds_b[64 * 256];
  __shared__ __align__(16) ushort_t lds_o[64][72];   // epilogue staging; also vT transpose staging
  __shared__ float lds_s[64];

  const int t = threadIdx.x;
  const bool isQ = (blockIdx.x >= (NCC / 64));
  const int row0 = isQ ? ((int)blockIdx.x - NCC / 64) * 64 : (int)blockIdx.x * 64;
  const float* In = isQ ? points_feat : box_feat;
  const ushort_t* WT = isQ ? WqT : WkT;
  const float* Bi = isQ ? bq : bk;
  ushort_t* Out = isQ ? q_out : kf_out;
  const int swz = isQ ? 0 : 7;

  // ---- preload the whole 64x256 row-tile: 4 rows x 4 col-blocks per thread ----
  const int r0 = t >> 4;        // 0..15: base row
  const int cj = (t & 15) * 4;  // col within a 64-col block
  float4 vld[4][4];             // [p(col-block)][i2(row-step)] -- static indices only
#pragma unroll
  for (int p = 0; p < 4; ++p)
#pragma unroll
    for (int i2 = 0; i2 < 4; ++i2)
      vld[p][i2] = *(const float4*)&In[(size_t)(row0 + r0 + 16 * i2) * DD + p * 64 + cj];

  if (t < 64) {
    float s = 1.0f;
    if (!isQ) {
      int c = row0 + t;
      float stride = centers[c * 4 + 3];
      int lvl = (int)(log2f(stride) + 0.5f) - 3;
      lvl = lvl < 0 ? 0 : (lvl > 4 ? 4 : lvl);
      s = scales[lvl];
      float hf = floorf(centers[c * 4 + 2] * 0.5f);
      xy[c] = make_float2(centers[c * 4 + 1] + hf, centers[c * 4 + 0] + hf);
    }
    lds_s[t] = s;
  }
  __syncthreads();

  float sc[4];
#pragma unroll
  for (int i2 = 0; i2 < 4; ++i2) sc[i2] = lds_s[r0 + 16 * i2];

  // ---- fused convert: lds_a (f16 scaled) + lt (bf16 transposed) per pass ----
  {
    ushort_t(*lt)[72] = lds_o;
#pragma unroll
    for (int p = 0; p < 4; ++p) {
#pragma unroll
      for (int i2 = 0; i2 < 4; ++i2) {
        const float4 v = vld[p][i2];
        const int row = r0 + 16 * i2;
        const float s = sc[i2];
        ushort_t h0 = f2h_bits(v.x * s), h1 = f2h_bits(v.y * s);
        ushort_t h2 = f2h_bits(v.z * s), h3 = f2h_bits(v.w * s);
        *(uint2*)&lds_a[row][p * 64 + cj] =
            make_uint2((unsigned)h0 | ((unsigned)h1 << 16), (unsigned)h2 | ((unsigned)h3 << 16));
        if (!isQ) {
          lt[cj + 0][row] = f2bf_bits(v.x);
          lt[cj + 1][row] = f2bf_bits(v.y);
          lt[cj + 2][row] = f2bf_bits(v.z);
          lt[cj + 3][row] = f2bf_bits(v.w);
        }
      }
      if (!isQ) {  // block-uniform -> barriers legal
        __syncthreads();
#pragma unroll
        for (int i3 = 0; i3 < 2; i3++) {
          int f = t + 256 * i3;  // 0..511 -> 64 d x 8 c-groups
          int d = f >> 3, jg = f & 7;
          int tile = (row0 >> 5) + (jg >> 2);
          size_t ob = (size_t)tile * (256 * VROW) + (size_t)(p * 64 + d) * VROW + (jg & 3) * 8;
          const uint2* src = (const uint2*)&lt[d][jg * 8];
          *(uint2*)&vTb[ob] = src[0];
          *(uint2*)&vTb[ob + 4] = src[1];
        }
        __syncthreads();  // copyout done before next pass overwrites lt
      }
    }
  }

  const int w = t >> 6, lane = t & 63, qd = lane >> 4, n = lane & 15;
  const int sw8 = (n & 7) * 8;

  for (int g = 0; g < 4; ++g) {
    __syncthreads();  // lds_b/lds_o reusable; covers A-stage + vT passes at g=0
#pragma unroll
    for (int j = 0; j < 8; ++j) {
      int sg = w * 8 + j;
      dma16(&WT[(size_t)g * 64 * DD + sg * 512 + lane * 8], &lds_b[sg * 512 + lane * 8]);
    }
    __syncthreads();

    floatx4 acc[4] = {};
#pragma unroll
    for (int s = 0; s < 8; s++) {
      half8 af = __builtin_bit_cast(half8, *(const uint4*)&lds_a[w * 16 + n][s * 32 + qd * 8]);
      int off = (s * 32 + qd * 8) ^ sw8;
#pragma unroll
      for (int nt = 0; nt < 4; ++nt) {
        half8 bf = __builtin_bit_cast(half8, *(const uint4*)&lds_b[(nt * 16 + n) * 256 + off]);
        acc[nt] = __builtin_amdgcn_mfma_f32_16x16x32_f16(af, bf, acc[nt], 0, 0, 0);
      }
    }
    // epilogue to lds_o (C/D: row=4qd+r, col=nt*16+n)
#pragma unroll
    for (int nt = 0; nt < 4; ++nt) {
      float b = Bi[g * 64 + nt * 16 + n];
#pragma unroll
      for (int r = 0; r < 4; r++) lds_o[w * 16 + qd * 4 + r][nt * 16 + n] = f2h_bits(acc[nt][r] + b);
    }
    __syncthreads();
    // coalesced copy-out with kf swizzle
#pragma unroll
    for (int i = 0; i < 2; i++) {
      int idx = t * 2 + i;
      int r = idx >> 3, grp = idx & 7;
      uint4 v = *(const uint4*)&lds_o[r][grp * 8];
      int grpS = grp ^ (swz & (r & 7));
      *(uint4*)&Out[(size_t)(row0 + r) * DD + (g * 8 + grpS) * 8] = v;
    }
  }
}

// ---------------------------------------------------------------------------
// K3: fused attention. FROZEN round-5 body (122.4us / 40.1MB fetch): round-0
// skeleton + array-free scalar-intrinsic substitutions (fmed3, exp2 builtin,
// native __bf16 cast). CLOSED LEVERS (measured): (1) local arrays +
// inline-asm packing -> ~600MB scratch spill (rounds 1-3); (2) occupancy
// >2 blocks/CU -> impossible: body needs ~256 regs/wave (128 acc in unified
// VGPR/AGPR file + 128 VGPR) = hard 2 waves/SIMD cap; forcing
// launch_bounds(256,4) spilled accumulators, 3.67GB traffic, 952us (round 7).
// Do not touch without a disasm diff.
// Block = 4 waves x 32 points; grid (64 chunks, 8 pg) = 512 blocks = exactly
// 2/CU. Single barrier per iter; kf+vT double-buffered, staged by DMA issued
// right after the barrier (drains at the NEXT barrier -> full-iter hiding).
// PART=true: per-chunk partials via plain stores; else atomicAdd fallback.
// ---------------------------------------------------------------------------
template <bool PART>
__global__ __launch_bounds__(256, 2) void attn_kernel(
    const ushort_t* __restrict__ qf16, const ushort_t* __restrict__ kf16,
    const ushort_t* __restrict__ vTb, const float2* __restrict__ xy,
    const float* __restrict__ boxes, float* __restrict__ acc_out,
    float* __restrict__ den_out) {
  __shared__ __align__(16) ushort_t lds_k[2][32 * 256];   // kf tile (swizzled rows)
  __shared__ __align__(16) ushort_t lds_v[2][256 * VROW]; // vT tile (padded rows)
  __shared__ __align__(16) ushort_t lds_p[4][32][VROW];   // per-wave P^T bf16

  const int t = threadIdx.x;
  const int w = t >> 6, lane = t & 63, qd = lane >> 4, n = lane & 15;
  const int chunk = blockIdx.x;
  const int p0w = blockIdx.y * 128 + w * 32;
  const int cchunk = chunk * 1024;
  const int sw16 = (n & 7) * 16;  // byte XOR for kf frag reads

  half8 qfr[2][8];
  float4 bxv[2];
#pragma unroll
  for (int pt = 0; pt < 2; ++pt) {
    int p = p0w + pt * 16 + n;
#pragma unroll
    for (int s = 0; s < 8; s++)
      qfr[pt][s] =
          __builtin_bit_cast(half8, *(const uint4*)&qf16[(size_t)p * DD + s * 32 + qd * 8]);
    bxv[pt] = *(const float4*)&boxes[p * 4];
  }

  floatx4 macc[2][16] = {};
  float dsum0 = 0.f, dsum1 = 0.f;

  auto stage = [&](int it, int buf) {
    const size_t kbase = (size_t)(cchunk + it * 32) * DD * 2;  // bytes
#pragma unroll
    for (int j = 0; j < 4; ++j) {
      int i = w * 4 + j;
      dma16((const char*)kf16 + kbase + i * 1024 + lane * 16,
            (char*)lds_k[buf] + i * 1024 + lane * 16);
    }
    const size_t vbase = (size_t)((cchunk >> 5) + it) * VTILE_B;
#pragma unroll
    for (int j = 0; j < 4; ++j) {
      int i = j * 4 + w;
      dma16((const char*)vTb + vbase + i * 1024 + lane * 16,
            (char*)lds_v[buf] + i * 1024 + lane * 16);
    }
    if (w < 2) {
      int i = 16 + w;
      dma16((const char*)vTb + vbase + i * 1024 + lane * 16,
            (char*)lds_v[buf] + i * 1024 + lane * 16);
    }
  };

  stage(0, 0);

  for (int it = 0; it < 32; ++it) {
    const int buf = it & 1;
    const int cb = cchunk + it * 32;
    __syncthreads();  // drains stage(it); prev iter's reads of buf^1 done
    if (it + 1 < 32) stage(it + 1, buf ^ 1);  // drains at NEXT barrier

    // QK^T from lds_k[buf] (XOR-swizzled rows, bank-balanced)
#pragma unroll
    for (int t2 = 0; t2 < 2; ++t2) {
      const char* krow = (const char*)lds_k[buf] + (t2 * 16 + n) * 512;
      floatx4 a0 = {}, a1 = {};
#pragma unroll
      for (int s = 0; s < 8; s++) {
        half8 af = __builtin_bit_cast(half8, *(const uint4*)(krow + ((s * 64 + qd * 16) ^ sw16)));
        a0 = __builtin_amdgcn_mfma_f32_16x16x32_f16(af, qfr[0][s], a0, 0, 0, 0);
        a1 = __builtin_amdgcn_mfma_f32_16x16x32_f16(af, qfr[1][s], a1, 0, 0, 0);
      }
      unsigned pk00 = 0, pk01 = 0, pk10 = 0, pk11 = 0;
#pragma unroll
      for (int r = 0; r < 4; r++) {
        int cl = t2 * 16 + qd * 4 + r;
        float2 pxy = xy[cb + cl];  // L1/L2-resident, wave-uniform per 16 lanes
        {
          float mn = fminf(fminf(pxy.x - bxv[0].x, pxy.y - bxv[0].y),
                           fminf(bxv[0].z - pxy.x, bxv[0].w - pxy.y));
          float sim = __builtin_amdgcn_fmed3f(a0[r], -50.f, 50.f);
          float e = (mn > 0.f) ? __builtin_amdgcn_exp2f((sim - 50.f) * 1.44269504f) : 0.f;
          dsum0 += e;
          unsigned b = (unsigned)f2bf_cast(e);
          if (r == 0) pk00 = b;
          else if (r == 1) pk00 |= b << 16;
          else if (r == 2) pk01 = b;
          else pk01 |= b << 16;
        }
        {
          float mn = fminf(fminf(pxy.x - bxv[1].x, pxy.y - bxv[1].y),
                           fminf(bxv[1].z - pxy.x, bxv[1].w - pxy.y));
          float sim = __builtin_amdgcn_fmed3f(a1[r], -50.f, 50.f);
          float e = (mn > 0.f) ? __builtin_amdgcn_exp2f((sim - 50.f) * 1.44269504f) : 0.f;
          dsum1 += e;
          unsigned b = (unsigned)f2bf_cast(e);
          if (r == 0) pk10 = b;
          else if (r == 1) pk10 |= b << 16;
          else if (r == 2) pk11 = b;
          else pk11 |= b << 16;
        }
      }
      *(uint2*)&lds_p[w][n][t2 * 16 + qd * 4] = make_uint2(pk00, pk01);
      *(uint2*)&lds_p[w][16 + n][t2 * 16 + qd * 4] = make_uint2(pk10, pk11);
    }
    // same-wave LDS RAW on lds_p (DS ops only; DMA uses vmcnt)
    __asm__ volatile("s_waitcnt lgkmcnt(0)" ::: "memory");

    const char* pr0 = (const char*)&lds_p[w][n][0];
    const char* pr1 = (const char*)&lds_p[w][16 + n][0];
    short8 a20 = mk_s8(*(const uint2*)(pr0 + qd * 16), *(const uint2*)(pr0 + qd * 16 + 8));
    short8 a21 = mk_s8(*(const uint2*)(pr1 + qd * 16), *(const uint2*)(pr1 + qd * 16 + 8));
#pragma unroll
    for (int dt = 0; dt < 16; ++dt) {
      const char* vrow = (const char*)lds_v[buf] + (dt * 16 + n) * (VROW * 2);
      short8 b2 = mk_s8(*(const uint2*)(vrow + qd * 16), *(const uint2*)(vrow + qd * 16 + 8));
      macc[0][dt] = __builtin_amdgcn_mfma_f32_16x16x32_bf16(a20, b2, macc[0][dt], 0, 0, 0);
      macc[1][dt] = __builtin_amdgcn_mfma_f32_16x16x32_bf16(a21, b2, macc[1][dt], 0, 0, 0);
    }
  }

  dsum0 += __shfl_xor(dsum0, 16, 64);
  dsum0 += __shfl_xor(dsum0, 32, 64);
  dsum1 += __shfl_xor(dsum1, 16, 64);
  dsum1 += __shfl_xor(dsum1, 32, 64);

  if (PART) {
    if (lane < 16) {
      den_out[(size_t)chunk * NPP + p0w + n] = dsum0;
      den_out[(size_t)chunk * NPP + p0w + 16 + n] = dsum1;
    }
    float* ab = acc_out + (size_t)chunk * NPP * DD;
#pragma unroll
    for (int pt = 0; pt < 2; ++pt)
#pragma unroll
      for (int dt = 0; dt < 16; ++dt)
#pragma unroll
        for (int r = 0; r < 4; r++)
          ab[(size_t)(p0w + pt * 16 + qd * 4 + r) * DD + dt * 16 + n] = macc[pt][dt][r];
  } else {
    if (lane < 16) {
      atomicAdd(&den_out[p0w + n], dsum0);
      atomicAdd(&den_out[p0w + 16 + n], dsum1);
    }
#pragma unroll
    for (int pt = 0; pt < 2; ++pt)
#pragma unroll
      for (int dt = 0; dt < 16; ++dt)
#pragma unroll
        for (int r = 0; r < 4; r++)
          atomicAdd(&acc_out[(size_t)(p0w + pt * 16 + qd * 4 + r) * DD + dt * 16 + n],
                    macc[pt][dt][r]);
  }
}

// ---------------------------------------------------------------------------
// K4a: reduce partials over chunks + finalize (PART path)
// ---------------------------------------------------------------------------
__global__ __launch_bounds__(256) void reduce_finalize(const float* __restrict__ points_feat,
                                                       const float* __restrict__ acc_part,
                                                       const float* __restrict__ den_part,
                                                       float* __restrict__ out) {
  const int p = blockIdx.x, t = threadIdx.x;
  float s = 0.f;
#pragma unroll 4
  for (int c = 0; c < NCHUNK; ++c) s += acc_part[((size_t)c * NPP + p) * DD + t];
  float dn = den_part[(size_t)(t & 63) * NPP + p];
#pragma unroll
  for (int o = 1; o < 64; o <<= 1) dn += __shfl_xor(dn, o, 64);
  float m = (dn > 0.f) ? s / dn : 0.f;
  out[(size_t)p * DD + t] = points_feat[(size_t)p * DD + t] + m;
}

// K4b: atomic-path finalize
__global__ void finalize(const float* __restrict__ points_feat, const float* __restrict__ acc,
                         const float* __restrict__ den, float* __restrict__ out) {
  int p = blockIdx.x, d = threadIdx.x;
  float dn = den[p];
  float m = (dn > 0.f) ? acc[p * DD + d] / dn : 0.f;
  out[p * DD + d] = points_feat[p * DD + d] + m;
}

extern "C" void kernel_launch(void* const* d_in, const int* in_sizes, int n_in, void* d_out,
                              int out_size, void* d_ws, size_t ws_size, hipStream_t stream) {
  const float* points_feat = (const float*)d_in[0];
  const float* box_feat = (const float*)d_in[1];
  const float* centers = (const float*)d_in[2];
  const float* boxes = (const float*)d_in[3];
  const float* Wq = (const float*)d_in[4];
  const float* bq = (const float*)d_in[5];
  const float* Wk = (const float*)d_in[6];
  const float* bk = (const float*)d_in[7];
  const float* scales = (const float*)d_in[8];

  char* p = (char*)d_ws;
  ushort_t* ws_q = (ushort_t*)p;        p += (size_t)NPP * DD * 2;
  ushort_t* ws_kf = (ushort_t*)p;       p += (size_t)NCC * DD * 2;
  ushort_t* ws_vTb = (ushort_t*)p;      p += (size_t)(NCC / 32) * VTILE_B;
  float2* ws_xy = (float2*)p;           p += (size_t)NCC * 8;
  ushort_t* ws_wqT = (ushort_t*)p;      p += (size_t)DD * DD * 2;
  ushort_t* ws_wkT = (ushort_t*)p;      p += (size_t)DD * DD * 2;
  float* ws_den = (float*)p;            p += (size_t)NCHUNK * NPP * 4;
  float* ws_acc = (float*)p;
  size_t need_part = (size_t)(p - (char*)d_ws) + (size_t)NCHUNK * NPP * DD * 4;
  const bool part = ws_size >= need_part;

  wt_prep<<<dim3(16, 2), 256, 0, stream>>>(Wq, Wk, ws_wqT, ws_wkT);
  prep_gemm<<<NCC / 64 + NPP / 64, 256, 0, stream>>>(box_feat, points_feat, centers, scales,
                                                     ws_wqT, ws_wkT, bq, bk, ws_q, ws_kf,
                                                     ws_vTb, ws_xy);
  if (part) {
    attn_kernel<true><<<dim3(NCHUNK, 8), 256, 0, stream>>>(ws_q, ws_kf, ws_vTb, ws_xy, boxes,
                                                           ws_acc, ws_den);
    reduce_finalize<<<NPP, 256, 0, stream>>>(points_feat, ws_acc, ws_den, (float*)d_out);
  } else {
    hipMemsetAsync(ws_den, 0, ((size_t)NPP * DD + NPP) * sizeof(float), stream);
    float* acc1 = ws_den + NPP;  // reuse region: den (1024) + acc (1024*256)
    attn_kernel<false><<<dim3(NCHUNK, 8), 256, 0, stream>>>(ws_q, ws_kf, ws_vTb, ws_xy, boxes,
                                                            acc1, ws_den);
    finalize<<<NPP, DD, 0, stream>>>(points_feat, acc1, ws_den, (float*)d_out);
  }
}

// Round 9
// 259.239 us; speedup vs baseline: 3.9553x; 1.0330x over previous
//
#include <hip/hip_runtime.h>

typedef unsigned short ushort_t;
typedef _Float16 half8 __attribute__((ext_vector_type(8)));
typedef short short8 __attribute__((ext_vector_type(8)));
typedef float floatx4 __attribute__((ext_vector_type(4)));

#define NCC 65536
#define NPP 1024
#define DD 256
#define NCHUNK 64
#define NQMICRO 128                  // q microblocks (16 rows x 128 cols each)
#define VROW 36                      // padded vT tile row, halves (72B: 16-phase banks)
#define VTILE_B (256 * VROW * 2)     // 18432 B per 32-candidate vT tile

static __device__ __forceinline__ ushort_t f2h_bits(float x) {
  _Float16 h = (_Float16)x;
  return __builtin_bit_cast(ushort_t, h);
}
static __device__ __forceinline__ ushort_t f2bf_bits(float x) {
  unsigned u = __builtin_bit_cast(unsigned, x);
  unsigned r = (u + 0x7FFFu + ((u >> 16) & 1u)) >> 16;
  return (ushort_t)r;
}
// native RNE f32->bf16 (fptrunc; compiler may fuse pairs into v_cvt_pk_bf16_f32)
static __device__ __forceinline__ ushort_t f2bf_cast(float x) {
  __bf16 h = (__bf16)x;
  return __builtin_bit_cast(ushort_t, h);
}

// async global->LDS DMA, 16B per lane (idiom verified rounds 2-3)
static __device__ __forceinline__ void dma16(const void* g, void* l) {
  __builtin_amdgcn_global_load_lds((const __attribute__((address_space(1))) unsigned int*)g,
                                   (__attribute__((address_space(3))) unsigned int*)l, 16, 0, 0);
}

static __device__ __forceinline__ short8 mk_s8(uint2 lo, uint2 hi) {
  uint4 u;
  u.x = lo.x; u.y = lo.y; u.z = hi.x; u.w = hi.y;
  return __builtin_bit_cast(short8, u);
}

// ---------------------------------------------------------------------------
// K0: transpose Wq/Wk (fp32 [k][n]) -> WT (f16 [n][k]), k' = k ^ ((n&7)<<3)
// ---------------------------------------------------------------------------
__global__ __launch_bounds__(256) void wt_prep(const float* __restrict__ Wq,
                                               const float* __restrict__ Wk,
                                               ushort_t* __restrict__ WqT,
                                               ushort_t* __restrict__ WkT) {
  __shared__ __align__(16) ushort_t lt[64][80];
  const float* W = blockIdx.y ? Wk : Wq;
  ushort_t* WT = blockIdx.y ? WkT : WqT;
  const int k0 = ((int)blockIdx.x & 3) * 64, n0 = ((int)blockIdx.x >> 2) * 64;
  const int t = threadIdx.x;
#pragma unroll
  for (int i = 0; i < 4; i++) {
    int f = t + 256 * i;
    int k = f >> 4, j = (f & 15) * 4;
    const float4 v = *(const float4*)&W[(size_t)(k0 + k) * DD + n0 + j];
    lt[j + 0][k] = f2h_bits(v.x);
    lt[j + 1][k] = f2h_bits(v.y);
    lt[j + 2][k] = f2h_bits(v.z);
    lt[j + 3][k] = f2h_bits(v.w);
  }
  __syncthreads();
#pragma unroll
  for (int i = 0; i < 2; i++) {
    int f = t + 256 * i;
    int nl = f >> 3, grp = f & 7;
    int n = n0 + nl;
    int kp = k0 + ((grp ^ (n & 7)) * 8);
    *(uint4*)&WT[(size_t)n * DD + kp] = *(const uint4*)&lt[nl][grp * 8];
  }
}

// ---------------------------------------------------------------------------
// K1: prep. Grid = 128 q-microblocks (FIRST) + 1024 kf blocks = 1152.
// Round 9 theory: old 1040-block grid at 2 blocks/CU (512 slots) forces a
// 3rd full round on 16 slots (3T makespan). 1024 kf = exactly 2x512; the
// 128 light q-micros (~0.35T: 2 WT stages, 16-row tile) run first and their
// slots absorb the overflow -> ~2.35T. Also: g-loop reduced 3->2 barriers
// with WT DMA issued AFTER the end-sync (all lds_b reads provably complete)
// so its flight overlaps copyout+barrier instead of draining cold.
// kf blocks: keyf (scaled, swizzled) + vTb transpose, single box_feat read.
// ---------------------------------------------------------------------------
__global__ __launch_bounds__(256) void prep_gemm(
    const float* __restrict__ box_feat, const float* __restrict__ points_feat,
    const float* __restrict__ centers, const float* __restrict__ scales,
    const ushort_t* __restrict__ WqT, const ushort_t* __restrict__ WkT,
    const float* __restrict__ bq, const float* __restrict__ bk,
    ushort_t* __restrict__ q_out, ushort_t* __restrict__ kf_out,
    ushort_t* __restrict__ vTb, float2* __restrict__ xy) {
  __shared__ __align__(16) ushort_t lds_a[64][264];
  __shared__ __align__(16) ushort_t lds_b[64 * 256];
  __shared__ __align__(16) ushort_t lds_o[64][72];   // epilogue staging; also vT transpose staging
  __shared__ float lds_s[64];

  const int t = threadIdx.x;
  const int w = t >> 6, lane = t & 63, qd = lane >> 4, n = lane & 15;
  const int sw8 = (n & 7) * 8;

  if (blockIdx.x < NQMICRO) {
    // ---- q microblock: 16 rows x 128 cols (2 g-groups), no scale/transpose ----
    const int m = (int)blockIdx.x;
    const int qrow0 = (m >> 1) * 16;       // 64 row-tiles x 16 rows = 1024 rows
    const int gbase = (m & 1) * 2;         // cols [gbase*64, gbase*64+128)
    // issue first WT tile early (flight overlaps A-stage)
#pragma unroll
    for (int j = 0; j < 8; ++j) {
      int sg = w * 8 + j;
      dma16(&WqT[(size_t)gbase * 64 * DD + sg * 512 + lane * 8], &lds_b[sg * 512 + lane * 8]);
    }
    // A-stage: 16 rows x 256 cols of points_feat -> lds_a (f16, scale = 1)
#pragma unroll
    for (int q = 0; q < 4; ++q) {
      const float4 v =
          *(const float4*)&points_feat[(size_t)(qrow0 + (t >> 4)) * DD + (t & 15) * 16 + q * 4];
      ushort_t h0 = f2h_bits(v.x), h1 = f2h_bits(v.y);
      ushort_t h2 = f2h_bits(v.z), h3 = f2h_bits(v.w);
      *(uint2*)&lds_a[t >> 4][(t & 15) * 16 + q * 4] =
          make_uint2((unsigned)h0 | ((unsigned)h1 << 16), (unsigned)h2 | ((unsigned)h3 << 16));
    }
#pragma unroll
    for (int gi = 0; gi < 2; ++gi) {
      const int g = gbase + gi;
      __syncthreads();  // drains WT DMA; A-stage (gi=0) / prior copyout (gi=1) visible
      floatx4 acc = {};
#pragma unroll
      for (int s = 0; s < 8; s++) {
        half8 af = __builtin_bit_cast(half8, *(const uint4*)&lds_a[n][s * 32 + qd * 8]);
        int off = (s * 32 + qd * 8) ^ sw8;
        half8 bf = __builtin_bit_cast(half8, *(const uint4*)&lds_b[(w * 16 + n) * 256 + off]);
        acc = __builtin_amdgcn_mfma_f32_16x16x32_f16(af, bf, acc, 0, 0, 0);
      }
      // epilogue: C row = qd*4+r (0..15), col = w*16+n (wave w owns nt=w)
      float b = bq[g * 64 + w * 16 + n];
#pragma unroll
      for (int r = 0; r < 4; r++) lds_o[qd * 4 + r][w * 16 + n] = f2h_bits(acc[r] + b);
      __syncthreads();  // epilogue visible; all lds_b reads done
      if (gi == 0) {    // stage second WT tile; flight overlaps copyout+loop sync
#pragma unroll
        for (int j = 0; j < 8; ++j) {
          int sg = w * 8 + j;
          dma16(&WqT[(size_t)(gbase + 1) * 64 * DD + sg * 512 + lane * 8],
                &lds_b[sg * 512 + lane * 8]);
        }
      }
      if (t < 128) {
        int r = t >> 3, grp = t & 7;
        uint4 v = *(const uint4*)&lds_o[r][grp * 8];
        *(uint4*)&q_out[(size_t)(qrow0 + r) * DD + (g * 8 + grp) * 8] = v;  // swz = 0
      }
    }
    return;
  }

  // ---- kf block: 64-row tile of box_feat -> kf_out (scaled, swizzled) + vTb ----
  const int row0 = ((int)blockIdx.x - NQMICRO) * 64;

  // issue WT g0 DMA first (flight overlaps preload + convert phases)
#pragma unroll
  for (int j = 0; j < 8; ++j) {
    int sg = w * 8 + j;
    dma16(&WkT[(size_t)sg * 512 + lane * 8], &lds_b[sg * 512 + lane * 8]);
  }

  // preload the whole 64x256 row-tile: 4 rows x 4 col-blocks per thread
  const int r0 = t >> 4;        // 0..15: base row
  const int cj = (t & 15) * 4;  // col within a 64-col block
  float4 vld[4][4];             // [p(col-block)][i2(row-step)] -- static indices only
#pragma unroll
  for (int p = 0; p < 4; ++p)
#pragma unroll
    for (int i2 = 0; i2 < 4; ++i2)
      vld[p][i2] = *(const float4*)&box_feat[(size_t)(row0 + r0 + 16 * i2) * DD + p * 64 + cj];

  if (t < 64) {
    int c = row0 + t;
    float stride = centers[c * 4 + 3];
    int lvl = (int)(log2f(stride) + 0.5f) - 3;
    lvl = lvl < 0 ? 0 : (lvl > 4 ? 4 : lvl);
    float s = scales[lvl];
    float hf = floorf(centers[c * 4 + 2] * 0.5f);
    xy[c] = make_float2(centers[c * 4 + 1] + hf, centers[c * 4 + 0] + hf);
    lds_s[t] = s;
  }
  __syncthreads();

  float sc[4];
#pragma unroll
  for (int i2 = 0; i2 < 4; ++i2) sc[i2] = lds_s[r0 + 16 * i2];

  // fused convert: lds_a (f16 scaled) + lt (bf16 transposed -> vTb) per pass
  {
    ushort_t(*lt)[72] = lds_o;
#pragma unroll
    for (int p = 0; p < 4; ++p) {
#pragma unroll
      for (int i2 = 0; i2 < 4; ++i2) {
        const float4 v = vld[p][i2];
        const int row = r0 + 16 * i2;
        const float s = sc[i2];
        ushort_t h0 = f2h_bits(v.x * s), h1 = f2h_bits(v.y * s);
        ushort_t h2 = f2h_bits(v.z * s), h3 = f2h_bits(v.w * s);
        *(uint2*)&lds_a[row][p * 64 + cj] =
            make_uint2((unsigned)h0 | ((unsigned)h1 << 16), (unsigned)h2 | ((unsigned)h3 << 16));
        lt[cj + 0][row] = f2bf_bits(v.x);
        lt[cj + 1][row] = f2bf_bits(v.y);
        lt[cj + 2][row] = f2bf_bits(v.z);
        lt[cj + 3][row] = f2bf_bits(v.w);
      }
      __syncthreads();
#pragma unroll
      for (int i3 = 0; i3 < 2; i3++) {
        int f = t + 256 * i3;  // 0..511 -> 64 d x 8 c-groups
        int d = f >> 3, jg = f & 7;
        int tile = (row0 >> 5) + (jg >> 2);
        size_t ob = (size_t)tile * (256 * VROW) + (size_t)(p * 64 + d) * VROW + (jg & 3) * 8;
        const uint2* src = (const uint2*)&lt[d][jg * 8];
        *(uint2*)&vTb[ob] = src[0];
        *(uint2*)&vTb[ob + 4] = src[1];
      }
      __syncthreads();  // copyout done before next pass overwrites lt
    }
  }

  // g-loop: 2 barriers per g; WT DMA for g+1 issued after end-sync so its
  // flight overlaps copyout + next top-sync (was: cold drain between syncs)
  for (int g = 0; g < 4; ++g) {
    __syncthreads();  // drains DMA(g); prior copyout of lds_o done
    floatx4 acc[4] = {};
#pragma unroll
    for (int s = 0; s < 8; s++) {
      half8 af = __builtin_bit_cast(half8, *(const uint4*)&lds_a[w * 16 + n][s * 32 + qd * 8]);
      int off = (s * 32 + qd * 8) ^ sw8;
#pragma unroll
      for (int nt = 0; nt < 4; ++nt) {
        half8 bf = __builtin_bit_cast(half8, *(const uint4*)&lds_b[(nt * 16 + n) * 256 + off]);
        acc[nt] = __builtin_amdgcn_mfma_f32_16x16x32_f16(af, bf, acc[nt], 0, 0, 0);
      }
    }
    // epilogue to lds_o (C/D: row=4qd+r, col=nt*16+n)
#pragma unroll
    for (int nt = 0; nt < 4; ++nt) {
      float b = bk[g * 64 + nt * 16 + n];
#pragma unroll
      for (int r = 0; r < 4; r++) lds_o[w * 16 + qd * 4 + r][nt * 16 + n] = f2h_bits(acc[nt][r] + b);
    }
    __syncthreads();  // epilogue visible; all waves' lds_b reads complete
    if (g < 3) {
#pragma unroll
      for (int j = 0; j < 8; ++j) {
        int sg = w * 8 + j;
        dma16(&WkT[(size_t)(g + 1) * 64 * DD + sg * 512 + lane * 8], &lds_b[sg * 512 + lane * 8]);
      }
    }
    // coalesced copy-out with kf swizzle (overlaps WT DMA flight)
#pragma unroll
    for (int i = 0; i < 2; i++) {
      int idx = t * 2 + i;
      int r = idx >> 3, grp = idx & 7;
      uint4 v = *(const uint4*)&lds_o[r][grp * 8];
      int grpS = grp ^ (7 & (r & 7));
      *(uint4*)&kf_out[(size_t)(row0 + r) * DD + (g * 8 + grpS) * 8] = v;
    }
  }
}

// ---------------------------------------------------------------------------
// K3: fused attention. FROZEN round-5 body (122.4us / 40.1MB fetch): round-0
// skeleton + array-free scalar-intrinsic substitutions (fmed3, exp2 builtin,
// native __bf16 cast). CLOSED LEVERS (measured): (1) local arrays +
// inline-asm packing -> ~600MB scratch spill (rounds 1-3); (2) occupancy
// >2 blocks/CU -> impossible: body needs ~256 regs/wave (128 acc in unified
// VGPR/AGPR file + 128 VGPR) = hard 2 waves/SIMD cap; forcing
// launch_bounds(256,4) spilled accumulators, 3.67GB traffic, 952us (round 7).
// Do not touch without a disasm diff.
// ---------------------------------------------------------------------------
template <bool PART>
__global__ __launch_bounds__(256, 2) void attn_kernel(
    const ushort_t* __restrict__ qf16, const ushort_t* __restrict__ kf16,
    const ushort_t* __restrict__ vTb, const float2* __restrict__ xy,
    const float* __restrict__ boxes, float* __restrict__ acc_out,
    float* __restrict__ den_out) {
  __shared__ __align__(16) ushort_t lds_k[2][32 * 256];   // kf tile (swizzled rows)
  __shared__ __align__(16) ushort_t lds_v[2][256 * VROW]; // vT tile (padded rows)
  __shared__ __align__(16) ushort_t lds_p[4][32][VROW];   // per-wave P^T bf16

  const int t = threadIdx.x;
  const int w = t >> 6, lane = t & 63, qd = lane >> 4, n = lane & 15;
  const int chunk = blockIdx.x;
  const int p0w = blockIdx.y * 128 + w * 32;
  const int cchunk = chunk * 1024;
  const int sw16 = (n & 7) * 16;  // byte XOR for kf frag reads

  half8 qfr[2][8];
  float4 bxv[2];
#pragma unroll
  for (int pt = 0; pt < 2; ++pt) {
    int p = p0w + pt * 16 + n;
#pragma unroll
    for (int s = 0; s < 8; s++)
      qfr[pt][s] =
          __builtin_bit_cast(half8, *(const uint4*)&qf16[(size_t)p * DD + s * 32 + qd * 8]);
    bxv[pt] = *(const float4*)&boxes[p * 4];
  }

  floatx4 macc[2][16] = {};
  float dsum0 = 0.f, dsum1 = 0.f;

  auto stage = [&](int it, int buf) {
    const size_t kbase = (size_t)(cchunk + it * 32) * DD * 2;  // bytes
#pragma unroll
    for (int j = 0; j < 4; ++j) {
      int i = w * 4 + j;
      dma16((const char*)kf16 + kbase + i * 1024 + lane * 16,
            (char*)lds_k[buf] + i * 1024 + lane * 16);
    }
    const size_t vbase = (size_t)((cchunk >> 5) + it) * VTILE_B;
#pragma unroll
    for (int j = 0; j < 4; ++j) {
      int i = j * 4 + w;
      dma16((const char*)vTb + vbase + i * 1024 + lane * 16,
            (char*)lds_v[buf] + i * 1024 + lane * 16);
    }
    if (w < 2) {
      int i = 16 + w;
      dma16((const char*)vTb + vbase + i * 1024 + lane * 16,
            (char*)lds_v[buf] + i * 1024 + lane * 16);
    }
  };

  stage(0, 0);

  for (int it = 0; it < 32; ++it) {
    const int buf = it & 1;
    const int cb = cchunk + it * 32;
    __syncthreads();  // drains stage(it); prev iter's reads of buf^1 done
    if (it + 1 < 32) stage(it + 1, buf ^ 1);  // drains at NEXT barrier

    // QK^T from lds_k[buf] (XOR-swizzled rows, bank-balanced)
#pragma unroll
    for (int t2 = 0; t2 < 2; ++t2) {
      const char* krow = (const char*)lds_k[buf] + (t2 * 16 + n) * 512;
      floatx4 a0 = {}, a1 = {};
#pragma unroll
      for (int s = 0; s < 8; s++) {
        half8 af = __builtin_bit_cast(half8, *(const uint4*)(krow + ((s * 64 + qd * 16) ^ sw16)));
        a0 = __builtin_amdgcn_mfma_f32_16x16x32_f16(af, qfr[0][s], a0, 0, 0, 0);
        a1 = __builtin_amdgcn_mfma_f32_16x16x32_f16(af, qfr[1][s], a1, 0, 0, 0);
      }
      unsigned pk00 = 0, pk01 = 0, pk10 = 0, pk11 = 0;
#pragma unroll
      for (int r = 0; r < 4; r++) {
        int cl = t2 * 16 + qd * 4 + r;
        float2 pxy = xy[cb + cl];  // L1/L2-resident, wave-uniform per 16 lanes
        {
          float mn = fminf(fminf(pxy.x - bxv[0].x, pxy.y - bxv[0].y),
                           fminf(bxv[0].z - pxy.x, bxv[0].w - pxy.y));
          float sim = __builtin_amdgcn_fmed3f(a0[r], -50.f, 50.f);
          float e = (mn > 0.f) ? __builtin_amdgcn_exp2f((sim - 50.f) * 1.44269504f) : 0.f;
          dsum0 += e;
          unsigned b = (unsigned)f2bf_cast(e);
          if (r == 0) pk00 = b;
          else if (r == 1) pk00 |= b << 16;
          else if (r == 2) pk01 = b;
          else pk01 |= b << 16;
        }
        {
          float mn = fminf(fminf(pxy.x - bxv[1].x, pxy.y - bxv[1].y),
                           fminf(bxv[1].z - pxy.x, bxv[1].w - pxy.y));
          float sim = __builtin_amdgcn_fmed3f(a1[r], -50.f, 50.f);
          float e = (mn > 0.f) ? __builtin_amdgcn_exp2f((sim - 50.f) * 1.44269504f) : 0.f;
          dsum1 += e;
          unsigned b = (unsigned)f2bf_cast(e);
          if (r == 0) pk10 = b;
          else if (r == 1) pk10 |= b << 16;
          else if (r == 2) pk11 = b;
          else pk11 |= b << 16;
        }
      }
      *(uint2*)&lds_p[w][n][t2 * 16 + qd * 4] = make_uint2(pk00, pk01);
      *(uint2*)&lds_p[w][16 + n][t2 * 16 + qd * 4] = make_uint2(pk10, pk11);
    }
    // same-wave LDS RAW on lds_p (DS ops only; DMA uses vmcnt)
    __asm__ volatile("s_waitcnt lgkmcnt(0)" ::: "memory");

    const char* pr0 = (const char*)&lds_p[w][n][0];
    const char* pr1 = (const char*)&lds_p[w][16 + n][0];
    short8 a20 = mk_s8(*(const uint2*)(pr0 + qd * 16), *(const uint2*)(pr0 + qd * 16 + 8));
    short8 a21 = mk_s8(*(const uint2*)(pr1 + qd * 16), *(const uint2*)(pr1 + qd * 16 + 8));
#pragma unroll
    for (int dt = 0; dt < 16; ++dt) {
      const char* vrow = (const char*)lds_v[buf] + (dt * 16 + n) * (VROW * 2);
      short8 b2 = mk_s8(*(const uint2*)(vrow + qd * 16), *(const uint2*)(vrow + qd * 16 + 8));
      macc[0][dt] = __builtin_amdgcn_mfma_f32_16x16x32_bf16(a20, b2, macc[0][dt], 0, 0, 0);
      macc[1][dt] = __builtin_amdgcn_mfma_f32_16x16x32_bf16(a21, b2, macc[1][dt], 0, 0, 0);
    }
  }

  dsum0 += __shfl_xor(dsum0, 16, 64);
  dsum0 += __shfl_xor(dsum0, 32, 64);
  dsum1 += __shfl_xor(dsum1, 16, 64);
  dsum1 += __shfl_xor(dsum1, 32, 64);

  if (PART) {
    if (lane < 16) {
      den_out[(size_t)chunk * NPP + p0w + n] = dsum0;
      den_out[(size_t)chunk * NPP + p0w + 16 + n] = dsum1;
    }
    float* ab = acc_out + (size_t)chunk * NPP * DD;
#pragma unroll
    for (int pt = 0; pt < 2; ++pt)
#pragma unroll
      for (int dt = 0; dt < 16; ++dt)
#pragma unroll
        for (int r = 0; r < 4; r++)
          ab[(size_t)(p0w + pt * 16 + qd * 4 + r) * DD + dt * 16 + n] = macc[pt][dt][r];
  } else {
    if (lane < 16) {
      atomicAdd(&den_out[p0w + n], dsum0);
      atomicAdd(&den_out[p0w + 16 + n], dsum1);
    }
#pragma unroll
    for (int pt = 0; pt < 2; ++pt)
#pragma unroll
      for (int dt = 0; dt < 16; ++dt)
#pragma unroll
        for (int r = 0; r < 4; r++)
          atomicAdd(&acc_out[(size_t)(p0w + pt * 16 + qd * 4 + r) * DD + dt * 16 + n],
                    macc[pt][dt][r]);
  }
}

// ---------------------------------------------------------------------------
// K4a: reduce partials over chunks + finalize (PART path)
// ---------------------------------------------------------------------------
__global__ __launch_bounds__(256) void reduce_finalize(const float* __restrict__ points_feat,
                                                       const float* __restrict__ acc_part,
                                                       const float* __restrict__ den_part,
                                                       float* __restrict__ out) {
  const int p = blockIdx.x, t = threadIdx.x;
  float s = 0.f;
#pragma unroll 4
  for (int c = 0; c < NCHUNK; ++c) s += acc_part[((size_t)c * NPP + p) * DD + t];
  float dn = den_part[(size_t)(t & 63) * NPP + p];
#pragma unroll
  for (int o = 1; o < 64; o <<= 1) dn += __shfl_xor(dn, o, 64);
  float m = (dn > 0.f) ? s / dn : 0.f;
  out[(size_t)p * DD + t] = points_feat[(size_t)p * DD + t] + m;
}

// K4b: atomic-path finalize
__global__ void finalize(const float* __restrict__ points_feat, const float* __restrict__ acc,
                         const float* __restrict__ den, float* __restrict__ out) {
  int p = blockIdx.x, d = threadIdx.x;
  float dn = den[p];
  float m = (dn > 0.f) ? acc[p * DD + d] / dn : 0.f;
  out[p * DD + d] = points_feat[p * DD + d] + m;
}

extern "C" void kernel_launch(void* const* d_in, const int* in_sizes, int n_in, void* d_out,
                              int out_size, void* d_ws, size_t ws_size, hipStream_t stream) {
  const float* points_feat = (const float*)d_in[0];
  const float* box_feat = (const float*)d_in[1];
  const float* centers = (const float*)d_in[2];
  const float* boxes = (const float*)d_in[3];
  const float* Wq = (const float*)d_in[4];
  const float* bq = (const float*)d_in[5];
  const float* Wk = (const float*)d_in[6];
  const float* bk = (const float*)d_in[7];
  const float* scales = (const float*)d_in[8];

  char* p = (char*)d_ws;
  ushort_t* ws_q = (ushort_t*)p;        p += (size_t)NPP * DD * 2;
  ushort_t* ws_kf = (ushort_t*)p;       p += (size_t)NCC * DD * 2;
  ushort_t* ws_vTb = (ushort_t*)p;      p += (size_t)(NCC / 32) * VTILE_B;
  float2* ws_xy = (float2*)p;           p += (size_t)NCC * 8;
  ushort_t* ws_wqT = (ushort_t*)p;      p += (size_t)DD * DD * 2;
  ushort_t* ws_wkT = (ushort_t*)p;      p += (size_t)DD * DD * 2;
  float* ws_den = (float*)p;            p += (size_t)NCHUNK * NPP * 4;
  float* ws_acc = (float*)p;
  size_t need_part = (size_t)(p - (char*)d_ws) + (size_t)NCHUNK * NPP * DD * 4;
  const bool part = ws_size >= need_part;

  wt_prep<<<dim3(16, 2), 256, 0, stream>>>(Wq, Wk, ws_wqT, ws_wkT);
  prep_gemm<<<NQMICRO + NCC / 64, 256, 0, stream>>>(box_feat, points_feat, centers, scales,
                                                    ws_wqT, ws_wkT, bq, bk, ws_q, ws_kf,
                                                    ws_vTb, ws_xy);
  if (part) {
    attn_kernel<true><<<dim3(NCHUNK, 8), 256, 0, stream>>>(ws_q, ws_kf, ws_vTb, ws_xy, boxes,
                                                           ws_acc, ws_den);
    reduce_finalize<<<NPP, 256, 0, stream>>>(points_feat, ws_acc, ws_den, (float*)d_out);
  } else {
    hipMemsetAsync(ws_den, 0, ((size_t)NPP * DD + NPP) * sizeof(float), stream);
    float* acc1 = ws_den + NPP;  // reuse region: den (1024) + acc (1024*256)
    attn_kernel<false><<<dim3(NCHUNK, 8), 256, 0, stream>>>(ws_q, ws_kf, ws_vTb, ws_xy, boxes,
                                                            acc1, ws_den);
    finalize<<<NPP, DD, 0, stream>>>(points_feat, acc1, ws_den, (float*)d_out);
  }
}